// Round 6
// baseline (242.935 us; speedup 1.0000x reference)
//
#include <hip/hip_runtime.h>

#define F        128     // feature width
#define NPB      128     // nodes per gather bucket
#define NPBS     7
#define NBMAX    1024    // max buckets -> n_nodes <= 131072 (also < 2^20 packing)
#define CHMAX    4096    // edges per sort chunk
#define NBLKMAX  512     // max chunks -> n_edges <= 2,097,152
#define CNTCAP   3072    // staged edges per bucket (mean 2048, +22 sigma)
#define SRTSZ    3968    // CNTCAP + NPB*7 (8-aligned CSR padding)
#define SPILLCAP 64      // block-local spill slots (cold, beyond +22 sigma)
#define BR       64      // fallback GEMM tile rows
#define KC       32      // fallback GEMM k-chunk

typedef short bf16x8 __attribute__((ext_vector_type(8)));
typedef float f32x4  __attribute__((ext_vector_type(4)));

__device__ __forceinline__ unsigned short f32_to_bf16_rne(float x) {
    unsigned u = __float_as_uint(x);
    u += 0x7fffu + ((u >> 16) & 1u);
    return (unsigned short)(u >> 16);
}

// ---------------------------------------------------------------------------
// Kernel 1 (K1): fused W-conversion + zero-row init + per-chunk counting sort.
// Block 0: convert W fp32->bf16 (64 KB) and zero hp row n_nodes (the pad row).
// Blocks 1..NBLK: locally sort chunk (bid-1) by 128-node bucket, write the
// sorted chunk CONTIGUOUSLY (fully coalesced) + its per-bucket offset row.
// No global bases, no count/scan kernels, no global atomics at all:
// the gather reconstructs each bucket as a concatenation of chunk slices.
// (r1/r2 lesson: random global atomic-returns wall at ~11 G/s; r5 lesson:
// count+scan+scatter = 3 serialized passes for one logical pass.)
// ---------------------------------------------------------------------------
__global__ __launch_bounds__(1024) void prep_sort_kernel(
        const float* __restrict__ Wf,
        unsigned short* __restrict__ Wb,
        unsigned short* __restrict__ hp,           // only row n_nodes touched here
        const int* __restrict__ src,
        const int* __restrict__ dst,
        int* __restrict__ excl,                    // [NBLK][NB+1] slice offsets
        int* __restrict__ sbuf,                    // [NBLK][CHMAX] sorted chunks
        int n_edges, int NB, int n_nodes) {
    const int tid = threadIdx.x;

    if (blockIdx.x == 0) {                         // conv W + zero pad row
        #pragma unroll
        for (int k = 0; k < 4; ++k) {
            int i = k * 1024 + tid;                // 4096 float4s total
            float4 v = *(const float4*)(Wf + 4 * (long)i);
            ushort4 o;
            o.x = f32_to_bf16_rne(v.x);
            o.y = f32_to_bf16_rne(v.y);
            o.z = f32_to_bf16_rne(v.z);
            o.w = f32_to_bf16_rne(v.w);
            *(ushort4*)(Wb + 4 * (long)i) = o;
        }
        if (tid < 64) ((int*)(hp + (size_t)n_nodes * F))[tid] = 0;
        return;
    }

    __shared__ int hist[NBMAX];
    __shared__ int cursor[NBMAX];
    __shared__ int sval[CHMAX];
    __shared__ int wsum[16];
    const int lane = tid & 63;
    const int w = tid >> 6;
    const int ch = blockIdx.x - 1;
    const int lo = ch * CHMAX;
    const int hi = min(n_edges, lo + CHMAX);
    const int len = hi - lo;

    int dd[4], ss[4];                              // register-staged chunk
    #pragma unroll
    for (int k = 0; k < 4; ++k) {
        int i = lo + k * 1024 + tid;
        bool ok = i < hi;
        dd[k] = ok ? dst[i] : -1;
        ss[k] = ok ? src[i] : 0;
    }
    for (int i = tid; i < NB; i += 1024) hist[i] = 0;
    __syncthreads();

    #pragma unroll
    for (int k = 0; k < 4; ++k)
        if (dd[k] >= 0) atomicAdd(&hist[((unsigned)dd[k]) >> NPBS], 1);
    __syncthreads();

    // exclusive scan over NB (<=1024) bucket counts
    const int own = (tid < NB) ? hist[tid] : 0;
    int v = own;
    #pragma unroll
    for (int d = 1; d < 64; d <<= 1) { int u = __shfl_up(v, d); if (lane >= d) v += u; }
    if (lane == 63) wsum[w] = v;
    __syncthreads();
    if (w == 0) {
        int s = (lane < 16) ? wsum[lane] : 0;
        #pragma unroll
        for (int d = 1; d < 16; d <<= 1) { int u = __shfl_up(s, d); if (lane >= d) s += u; }
        if (lane < 16) wsum[lane] = s;
    }
    __syncthreads();
    const int ex = v - own + ((w > 0) ? wsum[w - 1] : 0);
    int* eg = excl + (long)ch * (NB + 1);
    if (tid < NB) { eg[tid] = ex; cursor[tid] = ex; }
    if (tid == NB - 1) eg[NB] = ex + own;          // = len
    __syncthreads();

    // scatter into locally-sorted LDS array (int LDS atomics, proven fast)
    #pragma unroll
    for (int k = 0; k < 4; ++k)
        if (dd[k] >= 0) {
            int b = ((unsigned)dd[k]) >> NPBS;
            int p = atomicAdd(&cursor[b], 1);      // ds_add_rtn_u32
            sval[p] = ((dd[k] & (NPB - 1)) << 20) | ss[k];
        }
    __syncthreads();

    // flush: FULLY coalesced contiguous write of the sorted chunk
    int* ob = sbuf + (long)ch * CHMAX;
    for (int i = tid; i < len; i += 1024) ob[i] = sval[i];
}

// ---------------------------------------------------------------------------
// Kernel 2: h' = h @ W^T via MFMA bf16 (unchanged, proven).
// Algebraic reorder: segment_sum(h[src]) @ W^T == segment_sum((h@W^T)[src]).
// C layout (measured m89/m91): col=lane&15, row=quad*4+reg.
// ---------------------------------------------------------------------------
__global__ __launch_bounds__(256) void gemm_h_kernel(
        const float* __restrict__ h,
        const unsigned short* __restrict__ Wb,
        unsigned short* __restrict__ hp,          // [n+1][128] bf16 (row n = zeros)
        int n_rows) {
    const int wave = (blockIdx.x * 256 + threadIdx.x) >> 6;
    const int lane = threadIdx.x & 63;
    const int m0 = wave * 16;
    if (m0 >= n_rows) return;
    const int mn   = lane & 15;
    const int quad = lane >> 4;

    const int rowc = min(m0 + mn, n_rows - 1);
    const float* arow = h + (long)rowc * F + quad * 8;

    bf16x8 afr[4];
    #pragma unroll
    for (int kk = 0; kk < 4; ++kk) {
        float4 p0 = *(const float4*)(arow + kk * 32);
        float4 p1 = *(const float4*)(arow + kk * 32 + 4);
        bf16x8 f;
        f[0] = (short)f32_to_bf16_rne(p0.x);
        f[1] = (short)f32_to_bf16_rne(p0.y);
        f[2] = (short)f32_to_bf16_rne(p0.z);
        f[3] = (short)f32_to_bf16_rne(p0.w);
        f[4] = (short)f32_to_bf16_rne(p1.x);
        f[5] = (short)f32_to_bf16_rne(p1.y);
        f[6] = (short)f32_to_bf16_rne(p1.z);
        f[7] = (short)f32_to_bf16_rne(p1.w);
        afr[kk] = f;
    }

    f32x4 acc[8];
    #pragma unroll
    for (int t = 0; t < 8; ++t) acc[t] = (f32x4){0.f, 0.f, 0.f, 0.f};

    #pragma unroll
    for (int kk = 0; kk < 4; ++kk) {
        #pragma unroll
        for (int t = 0; t < 8; ++t) {
            const unsigned short* wp = Wb + (long)(t * 16 + mn) * F + kk * 32 + quad * 8;
            bf16x8 bfr = *(const bf16x8*)wp;
            acc[t] = __builtin_amdgcn_mfma_f32_16x16x32_bf16(afr[kk], bfr, acc[t], 0, 0, 0);
        }
    }

    #pragma unroll
    for (int t = 0; t < 8; ++t) {
        const int col = t * 16 + mn;
        #pragma unroll
        for (int r = 0; r < 4; ++r) {
            const int orow = m0 + quad * 4 + r;
            if (orow < n_rows)
                hp[(long)orow * F + col] = f32_to_bf16_rne(acc[t][r]);
        }
    }
}

// ---------------------------------------------------------------------------
// Kernel 3: per-bucket gather.  512 threads, ~34 KB LDS -> 4 blocks/CU; with
// NB=782 blocks ALL blocks are co-resident (r5 lesson: 391x16-wave blocks at
// 1.5/CU gave 48% occupancy).  Phases: slice descriptors -> scan -> slice
// copy into LDS staging -> per-node CSR with 8-ALIGNED zero-padded segments
// (pads point at hp's zero row) -> accumulate with NO per-slot masks:
// per 8 edges = 2 ds_read_b128 (ids) + 8 row loads + 16 unpack + 16 fadd.
// Spills (bucket > CNTCAP staged edges) go to block-LOCAL LDS (no global
// state, no memsets, no cross-block races).
// ---------------------------------------------------------------------------
__global__ __launch_bounds__(512) void bucket_gather_kernel(
        const unsigned short* __restrict__ hp,     // [n_nodes+1][128], row n = 0
        const int* __restrict__ excl,              // [NBLK][NB+1]
        const int* __restrict__ sbuf,              // [NBLK][CHMAX]
        const float* __restrict__ bias,
        float* __restrict__ out,
        int n_nodes, int NBLK, int NB) {
    __shared__ int lbase[NBLKMAX + 1];             // slice len -> scanned base
    __shared__ int lofs[NBLKMAX];                  // slice start within chunk
    __shared__ int stg[CNTCAP];                    // concatenated bucket edges
    __shared__ __align__(16) int srt[SRTSZ];       // 8-aligned per-node CSR
    __shared__ int hist[NPB];
    __shared__ int ofs[NPB + 1];
    __shared__ int cur[NPB];
    __shared__ int sdl[SPILLCAP];
    __shared__ int ssv[SPILLCAP];
    __shared__ int scnt;
    __shared__ int wsum[16];

    const int b = blockIdx.x;
    const int tid = threadIdx.x;
    const int lane = tid & 63;
    const int w = tid >> 6;

    // phase 0: per-chunk slice descriptors for this bucket
    for (int c = tid; c < NBLK; c += 512) {
        const int* er = excl + (long)c * (NB + 1) + b;
        int e0 = er[0];
        lofs[c] = e0;
        lbase[c] = er[1] - e0;                     // slice length (scan next)
    }
    if (tid < NPB) hist[tid] = 0;
    if (tid == 0) scnt = 0;
    if (NBLK == 0 && tid == 0) lbase[0] = 0;
    __syncthreads();

    // phase 1: exclusive scan of slice lengths (NBLK <= 512, 8 waves)
    {
        const int own = (tid < NBLK) ? lbase[tid] : 0;
        int v = own;
        #pragma unroll
        for (int d = 1; d < 64; d <<= 1) { int u = __shfl_up(v, d); if (lane >= d) v += u; }
        if (lane == 63) wsum[w] = v;
        __syncthreads();
        if (w == 0) {
            int s = (lane < 8) ? wsum[lane] : 0;
            #pragma unroll
            for (int d = 1; d < 8; d <<= 1) { int u = __shfl_up(s, d); if (lane >= d) s += u; }
            if (lane < 8) wsum[lane] = s;
        }
        __syncthreads();
        const int ex = v - own + ((w > 0) ? wsum[w - 1] : 0);
        if (tid < NBLK) lbase[tid] = ex;
        if (tid == NBLK - 1) lbase[NBLK] = ex + own;
    }
    __syncthreads();
    const int cnt = lbase[NBLK];
    const int cstg = min(cnt, CNTCAP);

    // phase 2: copy slices into contiguous LDS staging.  16-lane groups, 4
    // chunks per wave-iter (slice len avg ~5, P(len>16) ~ 6e-5 -> loop).
    for (int c0 = w * 4; c0 < NBLK; c0 += 32) {
        const int g = lane >> 4;
        const int c = c0 + g;
        const int li = lane & 15;
        int slen = 0, ob = 0, sb = 0;
        if (c < NBLK) { ob = lbase[c]; slen = lbase[c + 1] - ob; sb = lofs[c]; }
        for (int l = li; l < slen; l += 16) {
            int id = sbuf[(long)c * CHMAX + sb + l];
            int d2 = ob + l;
            if (d2 < CNTCAP) {
                stg[d2] = id;
            } else {                               // cold block-local spill
                int q = atomicAdd(&scnt, 1);
                if (q < SPILLCAP) { sdl[q] = id >> 20; ssv[q] = id & 0xFFFFF; }
            }
        }
    }
    __syncthreads();

    // phase 3: per-node degree histogram
    for (int e = tid; e < cstg; e += 512)
        atomicAdd(&hist[((unsigned)stg[e]) >> 20], 1);
    __syncthreads();

    // phase 4: init CSR array to zero-row sentinel; scan 8-PADDED degrees
    for (int i = tid; i < SRTSZ; i += 512) srt[i] = n_nodes;
    {
        const int own = (tid < NPB) ? hist[tid] : 0;
        const int pd = (own + 7) & ~7;
        int v = pd;
        #pragma unroll
        for (int d = 1; d < 64; d <<= 1) { int u = __shfl_up(v, d); if (lane >= d) v += u; }
        if (lane == 63) wsum[w] = v;
        __syncthreads();
        if (w == 0) {
            int s = (lane < 8) ? wsum[lane] : 0;
            #pragma unroll
            for (int d = 1; d < 8; d <<= 1) { int u = __shfl_up(s, d); if (lane >= d) s += u; }
            if (lane < 8) wsum[lane] = s;
        }
        __syncthreads();
        const int ex = v - pd + ((w > 0) ? wsum[w - 1] : 0);
        if (tid < NPB) { ofs[tid] = ex; cur[tid] = ex; }
        if (tid == NPB - 1) ofs[NPB] = ex + pd;
    }
    __syncthreads();

    // phase 5: scatter src ids into padded per-node segments
    for (int e = tid; e < cstg; e += 512) {
        int id = stg[e];
        int p = atomicAdd(&cur[((unsigned)id) >> 20], 1);  // ds_add_rtn_u32
        srt[p] = id & 0xFFFFF;
    }
    __syncthreads();

    // phase 6: register accumulation, mask-free (pads hit the zero row)
    const unsigned lo4 = lane << 2;                // this lane's dword in a row
    const float2 bv = *(const float2*)(bias + (lane << 1));
    const int ns = min(scnt, SPILLCAP);
    for (int nl = w; nl < NPB; nl += 8) {
        const int n = (b << NPBS) + nl;
        if (n >= n_nodes) break;
        const int beg = ofs[nl];
        const int pend = ofs[nl + 1];              // 8-aligned segment end

        float ax = 0.f, ay = 0.f;
        for (int i = beg; i < pend; i += 8) {
            const int4 ia = *(const int4*)&srt[i];       // ds_read_b128
            const int4 ib = *(const int4*)&srt[i + 4];   // ds_read_b128
            int sid[8] = {ia.x, ia.y, ia.z, ia.w, ib.x, ib.y, ib.z, ib.w};
            unsigned vv[8];
            #pragma unroll
            for (int j = 0; j < 8; ++j)
                vv[j] = *(const unsigned*)((const char*)hp +
                                           (((unsigned)sid[j] << 8) | lo4));
            #pragma unroll
            for (int j = 0; j < 8; ++j) {
                ax += __uint_as_float(vv[j] << 16);
                ay += __uint_as_float(vv[j] & 0xffff0000u);
            }
        }

        if (ns > 0) {                              // cold spill drain
            for (int k = 0; k < ns; ++k) {
                if (sdl[k] == nl) {
                    unsigned u = *(const unsigned*)((const char*)hp +
                                   (((unsigned)ssv[k] << 8) | lo4));
                    ax += __uint_as_float(u << 16);
                    ay += __uint_as_float(u & 0xffff0000u);
                }
            }
        }

        float rx = fmaxf(ax + bv.x, 0.f);
        float ry = fmaxf(ay + bv.y, 0.f);
        *(float2*)((char*)out + (((unsigned)n << 9) | (lane << 3))) =
            make_float2(rx, ry);
    }
}

// ---------------------------------------------------------------------------
// Fallback tier (tiny ws or oversize graph): atomic scatter + fp32 GEMM.
// ---------------------------------------------------------------------------
__global__ void scatter_add_kernel(const float* __restrict__ h,
                                   const int* __restrict__ src,
                                   const int* __restrict__ dst,
                                   float* __restrict__ agg,
                                   long total) {
    long stride = (long)gridDim.x * blockDim.x;
    for (long i = (long)blockIdx.x * blockDim.x + threadIdx.x; i < total; i += stride) {
        int e    = (int)(i >> 5);
        int lane = (int)(i & 31);
        int s = src[e];
        int d = dst[e];
        float4 v = *(const float4*)(h + (long)s * F + (lane << 2));
        float* o = agg + (long)d * F + (lane << 2);
        unsafeAtomicAdd(o + 0, v.x);
        unsafeAtomicAdd(o + 1, v.y);
        unsafeAtomicAdd(o + 2, v.z);
        unsafeAtomicAdd(o + 3, v.w);
    }
}

__global__ __launch_bounds__(256) void gemm_bias_relu_inplace(
        float* __restrict__ out,
        const float* __restrict__ W,
        const float* __restrict__ bias,
        int n_rows) {
    __shared__ __align__(16) float a_t[KC][BR + 4];
    __shared__ __align__(16) float w_t[KC][F + 4];
    const int tid = threadIdx.x;
    const int tx = tid & 15;
    const int ty = tid >> 4;
    const int row0 = blockIdx.x * BR;
    float acc[4][8];
    #pragma unroll
    for (int i = 0; i < 4; ++i)
        #pragma unroll
        for (int j = 0; j < 8; ++j) acc[i][j] = 0.f;
    for (int kc = 0; kc < F; kc += KC) {
        #pragma unroll
        for (int p = 0; p < 2; ++p) {
            int q = tid + p * 256, r = q >> 3, kq = q & 7;
            int row = row0 + r;
            float4 v = make_float4(0.f, 0.f, 0.f, 0.f);
            if (row < n_rows) v = *(const float4*)(out + (long)row * F + kc + (kq << 2));
            a_t[kq * 4 + 0][r] = v.x; a_t[kq * 4 + 1][r] = v.y;
            a_t[kq * 4 + 2][r] = v.z; a_t[kq * 4 + 3][r] = v.w;
        }
        #pragma unroll
        for (int p = 0; p < 4; ++p) {
            int q = tid + p * 256, j = q >> 3, kq = q & 7;
            float4 v = *(const float4*)(W + (long)j * F + kc + (kq << 2));
            w_t[kq * 4 + 0][j] = v.x; w_t[kq * 4 + 1][j] = v.y;
            w_t[kq * 4 + 2][j] = v.z; w_t[kq * 4 + 3][j] = v.w;
        }
        __syncthreads();
        #pragma unroll
        for (int k = 0; k < KC; ++k) {
            float4 av = *(const float4*)&a_t[k][ty << 2];
            float4 w0 = *(const float4*)&w_t[k][tx << 2];
            float4 w1 = *(const float4*)&w_t[k][64 + (tx << 2)];
            float a4[4] = {av.x, av.y, av.z, av.w};
            float wv[8] = {w0.x, w0.y, w0.z, w0.w, w1.x, w1.y, w1.z, w1.w};
            #pragma unroll
            for (int i = 0; i < 4; ++i)
                #pragma unroll
                for (int j = 0; j < 8; ++j) acc[i][j] += a4[i] * wv[j];
        }
        __syncthreads();
    }
    float4 b0 = *(const float4*)(bias + (tx << 2));
    float4 b1 = *(const float4*)(bias + 64 + (tx << 2));
    #pragma unroll
    for (int i = 0; i < 4; ++i) {
        int row = row0 + (ty << 2) + i;
        if (row < n_rows) {
            float4 r0, r1;
            r0.x = fmaxf(acc[i][0] + b0.x, 0.f); r0.y = fmaxf(acc[i][1] + b0.y, 0.f);
            r0.z = fmaxf(acc[i][2] + b0.z, 0.f); r0.w = fmaxf(acc[i][3] + b0.w, 0.f);
            r1.x = fmaxf(acc[i][4] + b1.x, 0.f); r1.y = fmaxf(acc[i][5] + b1.y, 0.f);
            r1.z = fmaxf(acc[i][6] + b1.z, 0.f); r1.w = fmaxf(acc[i][7] + b1.w, 0.f);
            *(float4*)(out + (long)row * F + (tx << 2)) = r0;
            *(float4*)(out + (long)row * F + 64 + (tx << 2)) = r1;
        }
    }
}

extern "C" void kernel_launch(void* const* d_in, const int* in_sizes, int n_in,
                              void* d_out, int out_size, void* d_ws, size_t ws_size,
                              hipStream_t stream) {
    const float* h   = (const float*)d_in[0];
    const int*   src = (const int*)d_in[1];
    const int*   dst = (const int*)d_in[2];
    const float* W   = (const float*)d_in[3];
    const float* b   = (const float*)d_in[4];
    float* out = (float*)d_out;

    const int n_nodes = in_sizes[0] / F;
    const int n_edges = in_sizes[1];
    const int NB   = (n_nodes + NPB - 1) >> NPBS;
    const int NBLK = (n_edges + CHMAX - 1) / CHMAX;

    // ws layout: excl | sbuf | hp (bf16 h@W^T, +1 zero row) | Wb
    auto al16 = [](size_t x) { return (x + 15) & ~(size_t)15; };
    const size_t off_excl = 0;
    const size_t off_sbuf = al16(off_excl + (size_t)NBLK * (NB + 1) * 4);
    const size_t off_hp   = al16(off_sbuf + (size_t)NBLK * CHMAX * 4);
    const size_t off_wb   = al16(off_hp + (size_t)(n_nodes + 1) * F * 2);
    const size_t need     = off_wb + (size_t)F * F * 2;

    if (ws_size >= need && n_nodes > 0 && NB <= NBMAX && NBLK <= NBLKMAX) {
        int* excl = (int*)((char*)d_ws + off_excl);
        int* sbuf = (int*)((char*)d_ws + off_sbuf);
        unsigned short* hp = (unsigned short*)((char*)d_ws + off_hp);
        unsigned short* Wb = (unsigned short*)((char*)d_ws + off_wb);

        prep_sort_kernel<<<NBLK + 1, 1024, 0, stream>>>(
            W, Wb, hp, src, dst, excl, sbuf, n_edges, NB, n_nodes);

        gemm_h_kernel<<<(n_nodes + 63) / 64, 256, 0, stream>>>(h, Wb, hp, n_nodes);

        bucket_gather_kernel<<<NB, 512, 0, stream>>>(
            hp, excl, sbuf, b, out, n_nodes, NBLK, NB);
    } else {
        hipMemsetAsync(out, 0, (size_t)out_size * sizeof(float), stream);
        scatter_add_kernel<<<16384, 256, 0, stream>>>(
            h, src, dst, out, (long)n_edges * 32);
        const int gblocks = (n_nodes + BR - 1) / BR;
        gemm_bias_relu_inplace<<<gblocks, 256, 0, stream>>>(out, W, b, n_nodes);
    }
}